// Round 6
// baseline (339.715 us; speedup 1.0000x reference)
//
#include <hip/hip_runtime.h>

#define NN 50000
#define NE 600000
#define DIM 128
#define NB_N 196   // ceil(50000/256)
#define NB_E 2344  // ceil(600000/256)
#define TILES 3125 // 50000/16
#define NEPAD (NE + 4 * NN + 64)  // rows padded to multiple of 4, min 4

typedef unsigned short u16;
typedef unsigned int u32;
typedef __attribute__((ext_vector_type(8))) short bf16x8;
typedef __attribute__((ext_vector_type(4))) float f32x4;

__device__ __forceinline__ u16 f2bf(float f) {
    u32 u = __builtin_bit_cast(u32, f);
    u32 r = (u + 0x7FFFu + ((u >> 16) & 1u)) >> 16;
    return (u16)r;
}
__device__ __forceinline__ float bflo(u32 w) { return __builtin_bit_cast(float, w << 16); }
__device__ __forceinline__ float bfhi(u32 w) { return __builtin_bit_cast(float, w & 0xffff0000u); }
__device__ __forceinline__ float i2f(int b) { return __builtin_bit_cast(float, b); }

// ---- CSR build (rows padded to multiple of 4, min 4; pad recs = {0,0}) -----

__global__ __launch_bounds__(256) void k_count(const int* __restrict__ ei,
                                               int* __restrict__ deg) {
    __shared__ int s64;
    if (threadIdx.x == 0) {
        int o = 0;
#pragma unroll
        for (int j = 0; j < 16; j++) o |= ei[2 * j + 1];  // int64 => high words 0
        s64 = (o == 0);
    }
    __syncthreads();
    int e = blockIdx.x * 256 + threadIdx.x;
    if (e >= NE) return;
    int d = s64 ? ei[2 * (NE + e)] : ei[NE + e];
    atomicAdd(&deg[d], 1);
}

__device__ __forceinline__ int pad4(int d) {
    int p = (d + 3) & ~3;
    return p < 4 ? 4 : p;
}

__global__ __launch_bounds__(256) void k_scanA(const int* __restrict__ deg,
                                               int* __restrict__ rp4,
                                               int* __restrict__ bsum) {
    __shared__ int buf[256];
    int t = threadIdx.x, i = blockIdx.x * 256 + t;
    int v = (i < NN) ? pad4(deg[i]) : 0;
    buf[t] = v;
    __syncthreads();
    for (int off = 1; off < 256; off <<= 1) {
        int x = (t >= off) ? buf[t - off] : 0;
        __syncthreads();
        buf[t] += x;
        __syncthreads();
    }
    if (i < NN) rp4[i] = buf[t] - v;
    if (t == 255) bsum[blockIdx.x] = buf[255];
}

__global__ __launch_bounds__(256) void k_scanB(int* __restrict__ bsum) {
    __shared__ int buf[256];
    int t = threadIdx.x;
    int v = (t < NB_N) ? bsum[t] : 0;
    buf[t] = v;
    __syncthreads();
    for (int off = 1; off < 256; off <<= 1) {
        int x = (t >= off) ? buf[t - off] : 0;
        __syncthreads();
        buf[t] += x;
        __syncthreads();
    }
    bsum[t] = buf[t] - v;
}

// finalize rp4, dinv; write zero pad records (no giant memset needed)
__global__ __launch_bounds__(256) void k_scanC(const int* __restrict__ deg,
                                               int* __restrict__ rp4,
                                               const int* __restrict__ bsum,
                                               float* __restrict__ dinv,
                                               int2* __restrict__ recs) {
    int i = blockIdx.x * 256 + threadIdx.x;
    if (i < NN) {
        int rp = rp4[i] + bsum[i >> 8];
        rp4[i] = rp;
        int d = deg[i];
        dinv[i] = rsqrtf((float)(d + 1));  // +1 self loop
        int p = pad4(d);
        for (int j = d; j < p; j++) recs[rp + j] = make_int2(0, 0);
    }
    if (i == 0) rp4[NN] = bsum[255];
}

// recs[pos] = {src, bits(norm)}
__global__ __launch_bounds__(256) void k_fill(const int* __restrict__ ei,
                                              const int* __restrict__ rp4,
                                              int* __restrict__ cursor,
                                              const float* __restrict__ dinv,
                                              int2* __restrict__ recs) {
    __shared__ int s64;
    if (threadIdx.x == 0) {
        int o = 0;
#pragma unroll
        for (int j = 0; j < 16; j++) o |= ei[2 * j + 1];
        s64 = (o == 0);
    }
    __syncthreads();
    int e = blockIdx.x * 256 + threadIdx.x;
    if (e >= NE) return;
    int is64 = s64;
    int s = is64 ? ei[2 * e] : ei[e];
    int d = is64 ? ei[2 * (NE + e)] : ei[NE + e];
    int pos = rp4[d] + atomicAdd(&cursor[d], 1);
    int2 rc;
    rc.x = s;
    rc.y = __builtin_bit_cast(int, dinv[s] * dinv[d]);
    recs[pos] = rc;
}

// ---- weight cast: Wt[layer][n][k] = bf16(W[layer][k][n]) -------------------
__global__ __launch_bounds__(256) void k_wcast(const float* __restrict__ W0,
                                               const float* __restrict__ W1,
                                               const float* __restrict__ W2,
                                               u16* __restrict__ Wt) {
    int idx = blockIdx.x * 256 + threadIdx.x;  // < 3*16384
    int l = idx >> 14, rem = idx & 16383;
    int n = rem >> 7, k = rem & 127;
    const float* W = (l == 0) ? W0 : ((l == 1) ? W1 : W2);
    Wt[idx] = f2bf(W[k * 128 + n]);
}

// ---- layer-1 GEMM: hw[N,128] = bf16(x f32) @ W0 ----------------------------
__global__ __launch_bounds__(256) void k_gemm_f32(const float* __restrict__ x,
                                                  const u16* __restrict__ Wt,
                                                  u16* __restrict__ hwb) {
    int lane = threadIdx.x & 63;
    int tile = blockIdx.x * 4 + (threadIdx.x >> 6);
    if (tile >= TILES) return;
    int r = lane & 15, q = lane >> 4;

    bf16x8 Bf[8][4];
#pragma unroll
    for (int nt = 0; nt < 8; nt++)
#pragma unroll
        for (int kc = 0; kc < 4; kc++)
            Bf[nt][kc] = *(const bf16x8*)(Wt + ((nt * 16 + r) << 7) + kc * 32 + q * 8);

    long rowbase = (long)tile * 16;
    bf16x8 Af[4];
#pragma unroll
    for (int kc = 0; kc < 4; kc++) {
        const float4* p = (const float4*)(x + (rowbase + r) * 128 + kc * 32 + q * 8);
        float4 t0 = p[0], t1 = p[1];
        bf16x8 a;
        a[0] = (short)f2bf(t0.x); a[1] = (short)f2bf(t0.y);
        a[2] = (short)f2bf(t0.z); a[3] = (short)f2bf(t0.w);
        a[4] = (short)f2bf(t1.x); a[5] = (short)f2bf(t1.y);
        a[6] = (short)f2bf(t1.z); a[7] = (short)f2bf(t1.w);
        Af[kc] = a;
    }

#pragma unroll
    for (int nt = 0; nt < 8; nt++) {
        f32x4 acc = {0.f, 0.f, 0.f, 0.f};
#pragma unroll
        for (int kc = 0; kc < 4; kc++)
            acc = __builtin_amdgcn_mfma_f32_16x16x32_bf16(Af[kc], Bf[nt][kc], acc, 0, 0, 0);
#pragma unroll
        for (int i = 0; i < 4; i++)
            hwb[(rowbase + q * 4 + i) * 128 + nt * 16 + r] = f2bf(acc[i]);
    }
}

// ---- GEMM (bf16 in): hw[N,128] = h @ W -------------------------------------
__global__ __launch_bounds__(256) void k_gemm(const u16* __restrict__ hb,
                                              const u16* __restrict__ Wt,
                                              u16* __restrict__ hwb) {
    int lane = threadIdx.x & 63;
    int tile = blockIdx.x * 4 + (threadIdx.x >> 6);
    if (tile >= TILES) return;
    int r = lane & 15, q = lane >> 4;

    bf16x8 Bf[8][4];
#pragma unroll
    for (int nt = 0; nt < 8; nt++)
#pragma unroll
        for (int kc = 0; kc < 4; kc++)
            Bf[nt][kc] = *(const bf16x8*)(Wt + ((nt * 16 + r) << 7) + kc * 32 + q * 8);

    long rowbase = (long)tile * 16;
    bf16x8 Af[4];
#pragma unroll
    for (int kc = 0; kc < 4; kc++)
        Af[kc] = *(const bf16x8*)(hb + ((rowbase + r) << 7) + kc * 32 + q * 8);

#pragma unroll
    for (int nt = 0; nt < 8; nt++) {
        f32x4 acc = {0.f, 0.f, 0.f, 0.f};
#pragma unroll
        for (int kc = 0; kc < 4; kc++)
            acc = __builtin_amdgcn_mfma_f32_16x16x32_bf16(Af[kc], Bf[nt][kc], acc, 0, 0, 0);
#pragma unroll
        for (int i = 0; i < 4; i++)
            hwb[(rowbase + q * 4 + i) * 128 + nt * 16 + r] = f2bf(acc[i]);
    }
}

// ---- feature-sliced aggregation: pass p gathers ONLY line p (32 feats) of
// each row -> 3.2 MB slab fits per-XCD L2. grid = 4 passes x 3125 tiles.
// Wave = 4 dst nodes; lane = chain*16 + e4*4 + fq:
//   chain: which dst node, e4: edge slot (4 edges/chain/iter), fq: 8-feat quad
__global__ __launch_bounds__(256) void k_agg4(const u16* __restrict__ hw_in,
                                              const int* __restrict__ rp4,
                                              const int2* __restrict__ recs,
                                              const float* __restrict__ dinv,
                                              const float* __restrict__ bias,
                                              u16* __restrict__ bf_out,
                                              float* __restrict__ f_out,
                                              int write_f32) {
    int pass = blockIdx.x / TILES;
    int tile = blockIdx.x - pass * TILES;
    int lane = threadIdx.x & 63;
    int w = threadIdx.x >> 6;
    int chain = lane >> 4, e4 = (lane >> 2) & 3, fq = lane & 3;
    int vbase = tile * 16 + w * 4;
    int base16 = pass * 32 + fq * 8;  // u16 offset of this lane's 8 feats

    int4 rlo = *(const int4*)(rp4 + vbase);
    int rhi = rp4[vbase + 4];
    int s_c = (chain == 0) ? rlo.x : (chain == 1) ? rlo.y : (chain == 2) ? rlo.z : rlo.w;
    int nxt = (chain == 0) ? rlo.y : (chain == 1) ? rlo.z : (chain == 2) ? rlo.w : rhi;
    int l_c = nxt - s_c;  // padded length, multiple of 4, >= 4
    int l_max = max(max(rlo.y - rlo.x, rlo.z - rlo.y), max(rlo.w - rlo.z, rhi - rlo.w));

    // self term (counted once: e4==0 lanes)
    uint4 sv = *(const uint4*)(hw_in + (size_t)(vbase + chain) * DIM + base16);
    float dv = dinv[vbase + chain];
    float sc = (e4 == 0) ? dv * dv : 0.0f;
    float acc[8];
    acc[0] = sc * bflo(sv.x); acc[1] = sc * bfhi(sv.x);
    acc[2] = sc * bflo(sv.y); acc[3] = sc * bfhi(sv.y);
    acc[4] = sc * bflo(sv.z); acc[5] = sc * bfhi(sv.z);
    acc[6] = sc * bflo(sv.w); acc[7] = sc * bfhi(sv.w);

    int nit = l_max >> 2;
    for (int it = 0; it < nit; ++it) {
        int eoff = 4 * it;
        int idx = s_c + min(eoff, l_c - 4) + e4;  // clamped re-read past row end
        int2 rc = recs[idx];
        uint4 u = *(const uint4*)(hw_in + (size_t)(u32)rc.x * DIM + base16);
        float n = (eoff < l_c) ? i2f(rc.y) : 0.0f;  // zero clamped re-reads
        acc[0] += n * bflo(u.x); acc[1] += n * bfhi(u.x);
        acc[2] += n * bflo(u.y); acc[3] += n * bfhi(u.y);
        acc[4] += n * bflo(u.z); acc[5] += n * bfhi(u.z);
        acc[6] += n * bflo(u.w); acc[7] += n * bfhi(u.w);
    }

    // reduce over e4 (lane bits 2-3)
#pragma unroll
    for (int j = 0; j < 8; j++) {
        acc[j] += __shfl_xor(acc[j], 4, 64);
        acc[j] += __shfl_xor(acc[j], 8, 64);
    }

    if (e4 == 0) {
        float4 b0 = ((const float4*)bias)[pass * 8 + fq * 2];
        float4 b1 = ((const float4*)bias)[pass * 8 + fq * 2 + 1];
        acc[0] = fmaxf(acc[0] + b0.x, 0.f); acc[1] = fmaxf(acc[1] + b0.y, 0.f);
        acc[2] = fmaxf(acc[2] + b0.z, 0.f); acc[3] = fmaxf(acc[3] + b0.w, 0.f);
        acc[4] = fmaxf(acc[4] + b1.x, 0.f); acc[5] = fmaxf(acc[5] + b1.y, 0.f);
        acc[6] = fmaxf(acc[6] + b1.z, 0.f); acc[7] = fmaxf(acc[7] + b1.w, 0.f);
        if (write_f32) {
            float4* p = (float4*)(f_out + (size_t)(vbase + chain) * DIM + base16);
            p[0] = make_float4(acc[0], acc[1], acc[2], acc[3]);
            p[1] = make_float4(acc[4], acc[5], acc[6], acc[7]);
        } else {
            uint4 pk;
            pk.x = (u32)f2bf(acc[0]) | ((u32)f2bf(acc[1]) << 16);
            pk.y = (u32)f2bf(acc[2]) | ((u32)f2bf(acc[3]) << 16);
            pk.z = (u32)f2bf(acc[4]) | ((u32)f2bf(acc[5]) << 16);
            pk.w = (u32)f2bf(acc[6]) | ((u32)f2bf(acc[7]) << 16);
            *(uint4*)(bf_out + (size_t)(vbase + chain) * DIM + base16) = pk;
        }
    }
}

// ---- launch ----------------------------------------------------------------

extern "C" void kernel_launch(void* const* d_in, const int* in_sizes, int n_in,
                              void* d_out, int out_size, void* d_ws, size_t ws_size,
                              hipStream_t stream) {
    const float* x = (const float*)d_in[0];
    const int* ei = (const int*)d_in[1];
    const float* W0 = (const float*)d_in[2];
    const float* b0 = (const float*)d_in[3];
    const float* W1 = (const float*)d_in[4];
    const float* b1 = (const float*)d_in[5];
    const float* W2 = (const float*)d_in[6];
    const float* b2 = (const float*)d_in[7];

    char* ws = (char*)d_ws;
    size_t off = 0;
    auto alloc = [&](size_t bytes) -> void* {
        void* p = ws + off;
        off += (bytes + 511) & ~(size_t)511;
        return p;
    };
    int* deg = (int*)alloc(NN * 4);      // zeroed
    int* cursor = (int*)alloc(NN * 4);   // zeroed
    size_t zbytes = off;
    int2* recs = (int2*)alloc((size_t)NEPAD * 8);  // pads written by k_scanC
    float* dinv = (float*)alloc(NN * 4);
    int* rp4 = (int*)alloc((NN + 1) * 4);
    int* bsum = (int*)alloc(256 * 4);
    u16* Wt = (u16*)alloc(3 * 128 * 128 * 2);
    u16* hwA = (u16*)alloc((size_t)NN * DIM * 2);
    u16* hB = (u16*)alloc((size_t)NN * DIM * 2);

    hipMemsetAsync(ws, 0, zbytes, stream);
    k_count<<<NB_E, 256, 0, stream>>>(ei, deg);
    k_scanA<<<NB_N, 256, 0, stream>>>(deg, rp4, bsum);
    k_scanB<<<1, 256, 0, stream>>>(bsum);
    k_scanC<<<NB_N, 256, 0, stream>>>(deg, rp4, bsum, dinv, recs);
    k_fill<<<NB_E, 256, 0, stream>>>(ei, rp4, cursor, dinv, recs);
    k_wcast<<<192, 256, 0, stream>>>(W0, W1, W2, Wt);

    k_gemm_f32<<<(TILES + 3) / 4, 256, 0, stream>>>(x, Wt, hwA);
    k_agg4<<<4 * TILES, 256, 0, stream>>>(hwA, rp4, recs, dinv, b0,
                                          hB, nullptr, 0);
    k_gemm<<<(TILES + 3) / 4, 256, 0, stream>>>(hB, Wt + 16384, hwA);
    k_agg4<<<4 * TILES, 256, 0, stream>>>(hwA, rp4, recs, dinv, b1,
                                          hB, nullptr, 0);
    k_gemm<<<(TILES + 3) / 4, 256, 0, stream>>>(hB, Wt + 32768, hwA);
    k_agg4<<<4 * TILES, 256, 0, stream>>>(hwA, rp4, recs, dinv, b2,
                                          nullptr, (float*)d_out, 1);
}